// Round 2
// baseline (92.817 us; speedup 1.0000x reference)
//
#include <hip/hip_runtime.h>
#include <hip/hip_bf16.h>

// Problem constants
// B=2, S=2048, D=512, H=8, DH=64, P=10, M = B*S = 4096
// scores = (QK^T + Q.rel_k[clamp])/sqrt(512); out = (scores.V + scores.rel_v) @ W0 + b0

typedef __attribute__((ext_vector_type(8)))  short  short8;
typedef __attribute__((ext_vector_type(4)))  short  short4v;
typedef __attribute__((ext_vector_type(4)))  int    int4v;
typedef __attribute__((ext_vector_type(16))) float  f32x16;
typedef __attribute__((ext_vector_type(8)))  __bf16 bf16x8;

#define DEV static __device__ __forceinline__

constexpr float INV_SCALE = 0.044194173824159216f; // 1/sqrt(512)

DEV unsigned short f2bs(float f){ __hip_bfloat16 h = __float2bfloat16(f); unsigned short u; __builtin_memcpy(&u,&h,2); return u; }
DEV short f2b(float f){ return (short)f2bs(f); }
DEV int   pk2(float a, float b){ return (int)((unsigned)f2bs(a) | ((unsigned)f2bs(b) << 16)); }
DEV bf16x8 ld8s(const short* p){ return __builtin_bit_cast(bf16x8, *(const short8*)p); }
DEV f32x16 z16(){ f32x16 z;
#pragma unroll
  for (int i=0;i<16;++i) z[i]=0.f;
  return z; }
DEV f32x16 mfma32(bf16x8 a, bf16x8 b, f32x16 c){ return __builtin_amdgcn_mfma_f32_32x32x16_bf16(a,b,c,0,0,0); }

// ---------------------------------------------------------------------------
// Weight transpose + cvt: WT[n][k] = bf16(W[k][n]) for Wq,Wk,Wv,W0
// ---------------------------------------------------------------------------
struct WtArgs { const float* W[4]; short* O[4]; };

__global__ __launch_bounds__(256) void wt_kernel(WtArgs args){
  const float* W = args.W[blockIdx.z];
  short* O = args.O[blockIdx.z];
  const int kt = blockIdx.x*64, nt = blockIdx.y*64;
  __shared__ float t[64][65];
  const int tid = threadIdx.x;
#pragma unroll
  for (int p=0;p<4;++p){
    int idx = p*1024 + tid*4; int r = idx>>6, c = idx&63;
    float4 v = *(const float4*)(W + (size_t)(kt+r)*512 + nt + c);
    t[r][c]=v.x; t[r][c+1]=v.y; t[r][c+2]=v.z; t[r][c+3]=v.w;
  }
  __syncthreads();
#pragma unroll
  for (int p=0;p<4;++p){
    int idx = p*1024 + tid*4; int n = idx>>6, k = idx&63;
    short4v o = { f2b(t[k][n]), f2b(t[k+1][n]), f2b(t[k+2][n]), f2b(t[k+3][n]) };
    *(short4v*)(O + (size_t)(nt+n)*512 + kt + k) = o;
  }
}

// ---------------------------------------------------------------------------
// GEMM: C[M=4096][512] = A[4096][512] @ W[512][512] + bias  (B given as WT[n][k])
// BM=128, BN=64, BK=64; 4 waves, wave w owns rows [w*32,w*32+32), all 64 cols.
// LDS rows are 128B with 16B-chunk XOR swizzle (chunk ^ (row&7)).
// ---------------------------------------------------------------------------
template<bool AF32, bool OUTB16>
DEV void gemm_body(const void* A, const short* BT, const float* bias, void* C,
                   int m0, int n0, short* Alds, short* Blds){
  const int tid = threadIdx.x, lane = tid&63, wid = tid>>6, lo5 = lane&31, hi = lane>>5;
  f32x16 acc0 = z16(), acc1 = z16();
  for (int kt=0; kt<8; ++kt){
    const int k0 = kt*64;
    __syncthreads();
    {
      const int rr = tid>>3, c = tid&7;
#pragma unroll
      for (int p=0;p<4;++p){
        int row = p*32 + rr;
        short8 v;
        if (AF32){
          const float* ap = (const float*)A + (size_t)(m0+row)*512 + k0 + c*8;
          float4 x = *(const float4*)ap; float4 y = *(const float4*)(ap+4);
          v = short8{ f2b(x.x),f2b(x.y),f2b(x.z),f2b(x.w), f2b(y.x),f2b(y.y),f2b(y.z),f2b(y.w) };
        } else {
          v = *(const short8*)((const short*)A + (size_t)(m0+row)*512 + k0 + c*8);
        }
        *(short8*)&Alds[row*64 + ((c ^ (row&7))*8)] = v;
      }
#pragma unroll
      for (int p=0;p<2;++p){
        int row = p*32 + rr;
        short8 v = *(const short8*)(BT + (size_t)(n0+row)*512 + k0 + c*8);
        *(short8*)&Blds[row*64 + ((c ^ (row&7))*8)] = v;
      }
    }
    __syncthreads();
#pragma unroll
    for (int da=0; da<4; ++da){
      const int arow = wid*32 + lo5;
      bf16x8 af = ld8s(&Alds[arow*64 + (((2*da+hi) ^ (arow&7))*8)]);
      const int b0r = lo5, b1r = 32+lo5;
      bf16x8 bf0 = ld8s(&Blds[b0r*64 + (((2*da+hi) ^ (b0r&7))*8)]);
      bf16x8 bf1 = ld8s(&Blds[b1r*64 + (((2*da+hi) ^ (b1r&7))*8)]);
      acc0 = mfma32(af, bf0, acc0);
      acc1 = mfma32(af, bf1, acc1);
    }
  }
  const float bv0 = bias[n0 + lo5], bv1 = bias[n0 + 32 + lo5];
#pragma unroll
  for (int r=0;r<16;++r){
    const int m = m0 + wid*32 + (r&3) + 8*(r>>2) + 4*hi;
    const float v0 = acc0[r] + bv0, v1 = acc1[r] + bv1;
    if (OUTB16){
      ((short*)C)[(size_t)m*512 + n0 + lo5]      = f2b(v0);
      ((short*)C)[(size_t)m*512 + n0 + 32 + lo5] = f2b(v1);
    } else {
      ((float*)C)[(size_t)m*512 + n0 + lo5]      = v0;
      ((float*)C)[(size_t)m*512 + n0 + 32 + lo5] = v1;
    }
  }
}

struct ProjArgs { const float* A[3]; const short* BT[3]; const float* bias[3]; short* C[3]; };

__global__ __launch_bounds__(256) void proj_gemm(ProjArgs args){
  __shared__ short Alds[128*64];
  __shared__ short Blds[64*64];
  const int z = blockIdx.z;
  gemm_body<true,true>(args.A[z], args.BT[z], args.bias[z], args.C[z],
                       blockIdx.x*128, blockIdx.y*64, Alds, Blds);
}

__global__ __launch_bounds__(256) void out_gemm(const short* A, const short* BT, const float* bias, float* C){
  __shared__ short Alds[128*64];
  __shared__ short Blds[64*64];
  gemm_body<false,false>(A, BT, bias, C, blockIdx.x*128, blockIdx.y*64, Alds, Blds);
}

// ---------------------------------------------------------------------------
// V transpose per head: Vp[b][s][h*64+dh] -> Vt[(b*8+h)][dh][s]
// ---------------------------------------------------------------------------
__global__ __launch_bounds__(256) void vt_kernel(const short* Vp, short* Vt){
  const int bh = blockIdx.y, s0 = blockIdx.x*64;
  const int b = bh>>3, h = bh&7;
  __shared__ short t[64][72];
  const int tid = threadIdx.x;
#pragma unroll
  for (int p=0;p<2;++p){
    int row = p*32 + (tid>>3), cc = (tid&7)*8;
    short8 v = *(const short8*)(Vp + (size_t)(b*2048 + s0 + row)*512 + h*64 + cc);
#pragma unroll
    for (int i=0;i<8;++i) t[row][cc+i] = v[i];
  }
  __syncthreads();
#pragma unroll
  for (int p=0;p<2;++p){
    int d = p*32 + (tid>>3), sc = (tid&7)*8;
    short8 o;
#pragma unroll
    for (int i=0;i<8;++i) o[i] = t[sc+i][d];
    *(short8*)(Vt + ((size_t)bh*64 + d)*2048 + s0 + sc) = o;
  }
}

// ---------------------------------------------------------------------------
// Fused linear attention with relative position terms.
// Grid: (qt 0..15, bh 0..15, ks 0..1). 256 thr = 4 waves; wave owns 32 q rows.
// Per (b,h,q-tile,ks): iterate 16 k-tiles of 64.
//   scores^T tile via mfma(Kfrag, Qfrag); + Rq lookup; bins/diag accumulation;
//   repack scores to bf16 A-frags (shfl half-swap); PV mfma against Vt tile.
// Epilogue: W2 = CS(128x32 bf16) x rel_vT(32x64 bf16) via 4 MFMAs.
// Writes fp32 partials to slab[ks].
// ---------------------------------------------------------------------------
__global__ __launch_bounds__(256) void attn_kernel(const short* Qp, const short* Kp, const short* Vt,
                                                   const float* relk_g, const float* relv_g, float* slab){
  const int qt = blockIdx.x, bh = blockIdx.y, ks = blockIdx.z;
  const int b = bh>>3, h = bh&7;
  const int tid = threadIdx.x, lane = tid&63, wid = tid>>6, lo5 = lane&31, hi = lane>>5;
  const int q0 = qt*128, qw = q0 + wid*32;

  __shared__ short Klds[64*64];
  __shared__ short Vl[64*64];
  __shared__ float Rq[128*21];
  __shared__ short CS[128*32];
  __shared__ short RVT[64*32];

  // init CS = 0; RVT[d][j] = bf16(rel_v[j][d]) (j<21 else 0), 16B-swizzled rows
  for (int i=tid; i<2048; i+=256) ((int*)CS)[i] = 0;
  for (int i=tid; i<2048; i+=256){
    int d = i>>5, j = i&31;
    RVT[d*32 + (j ^ ((d&3)<<3))] = (j<21) ? f2b(relv_g[j*64+d]) : (short)0;
  }

  // Q fragments (lane lo5 -> q row qw+lo5; elems 16*da + 8*hi + i)
  bf16x8 qf[4];
  {
    const short* Qrow = Qp + (size_t)(b*2048 + qw + lo5)*512 + h*64 + hi*8;
#pragma unroll
    for (int da=0;da<4;++da) qf[da] = ld8s(Qrow + da*16);
  }

  // Rq[q][j] = Q[q] . rel_k[j]  via 4 MFMAs (Q frags as A, rel_k rows as B cols)
  {
    f32x16 rq = z16();
    const int jr = lo5 <= 20 ? lo5 : 20;
    const float* rp = relk_g + jr*64 + hi*8;
#pragma unroll
    for (int da=0;da<4;++da){
      const float* p = rp + da*16;
      float4 x = *(const float4*)p; float4 y = *(const float4*)(p+4);
      short8 rb = { f2b(x.x),f2b(x.y),f2b(x.z),f2b(x.w), f2b(y.x),f2b(y.y),f2b(y.z),f2b(y.w) };
      rq = mfma32(qf[da], __builtin_bit_cast(bf16x8, rb), rq);
    }
    if (lo5 <= 20){
#pragma unroll
      for (int r=0;r<16;++r){
        int qoff = (r&3) + 8*(r>>2) + 4*hi;
        Rq[(wid*32 + qoff)*21 + lo5] = rq[r];
      }
    }
  }
  __syncthreads();

  const int qrow = wid*32 + lo5;   // local q (s-domain: this lane's column)
  const int qg = q0 + qrow;        // global q
  const float r0  = Rq[qrow*21 + 0];
  const float r20 = Rq[qrow*21 + 20];
  float bin0 = 0.f, bin20 = 0.f;
  f32x16 w1a = z16(), w1b = z16();

  const short* Kg = Kp + (size_t)b*2048*512 + h*64;
  const short* Vg = Vt + (size_t)bh*64*2048;

  for (int kt=0; kt<16; ++kt){
    const int k0 = ks*1024 + kt*64;
    __syncthreads();
    {
      const int rr = tid>>3, c = tid&7;
#pragma unroll
      for (int p=0;p<2;++p){
        int row = p*32 + rr;
        short8 v = *(const short8*)(Kg + (size_t)(k0+row)*512 + c*8);
        *(short8*)&Klds[row*64 + ((c ^ (row&7))*8)] = v;
      }
#pragma unroll
      for (int p=0;p<2;++p){
        int d = p*32 + rr;
        short8 v = *(const short8*)(Vg + (size_t)d*2048 + k0 + c*8);
        *(short8*)&Vl[d*64 + ((c ^ (d&7))*8)] = v;
      }
    }
    __syncthreads();

#pragma unroll
    for (int ksub=0; ksub<2; ++ksub){
      const int kb = k0 + ksub*32;
      // scores^T: D[m=k][n=q]
      f32x16 acc = z16();
#pragma unroll
      for (int da=0;da<4;++da){
        const int arow = ksub*32 + lo5;
        bf16x8 af = ld8s(&Klds[arow*64 + (((2*da+hi) ^ (arow&7))*8)]);
        acc = mfma32(af, qf[da], acc);
      }
      float s[16];
      if (kb + 31 <= qw - 10){            // whole subtile strictly below diag-band for all wave rows
#pragma unroll
        for (int r=0;r<16;++r){ float sv = (acc[r] + r0)*INV_SCALE; bin0 += sv; s[r]=sv; }
      } else if (kb >= qw + 41){          // strictly above
#pragma unroll
        for (int r=0;r<16;++r){ float sv = (acc[r] + r20)*INV_SCALE; bin20 += sv; s[r]=sv; }
      } else {
#pragma unroll
        for (int r=0;r<16;++r){
          const int krow = kb + (r&3) + 8*(r>>2) + 4*hi;
          const int delta = krow - qg;
          float rel;
          if (delta <= -10) rel = r0;
          else if (delta >= 10) rel = r20;
          else rel = Rq[qrow*21 + delta + 10];
          const float sv = (acc[r] + rel)*INV_SCALE;
          if (delta <= -10) bin0 += sv;
          else if (delta >= 10) bin20 += sv;
          else CS[qrow*32 + ((delta+10) ^ ((qrow&3)<<3))] = f2b(sv);
          s[r] = sv;
        }
      }
      // repack scores into PV A-frags (k split across lane halves)
      const int x0 = pk2(s[0],s[1]),   x1 = pk2(s[2],s[3]);
      const int y0 = pk2(s[4],s[5]),   y1 = pk2(s[6],s[7]);
      const int x2 = pk2(s[8],s[9]),   x3 = pk2(s[10],s[11]);
      const int y2 = pk2(s[12],s[13]), y3 = pk2(s[14],s[15]);
      const int x0s=__shfl_xor(x0,32,64), x1s=__shfl_xor(x1,32,64);
      const int y0s=__shfl_xor(y0,32,64), y1s=__shfl_xor(y1,32,64);
      const int x2s=__shfl_xor(x2,32,64), x3s=__shfl_xor(x3,32,64);
      const int y2s=__shfl_xor(y2,32,64), y3s=__shfl_xor(y3,32,64);
      const bool lo = (hi==0);
      int4v A0 = { lo?x0:y0s, lo?x1:y1s, lo?x0s:y0, lo?x1s:y1 };
      int4v A1 = { lo?x2:y2s, lo?x3:y3s, lo?x2s:y2, lo?x3s:y3 };
      const bf16x8 pa0 = __builtin_bit_cast(bf16x8, A0);
      const bf16x8 pa1 = __builtin_bit_cast(bf16x8, A1);
#pragma unroll
      for (int c=0;c<2;++c){
        const bf16x8 pa = c ? pa1 : pa0;
        const int chunk = ksub*4 + 2*c + hi;
        {
          const int d = lo5;
          bf16x8 vb = ld8s(&Vl[d*64 + ((chunk ^ (d&7))*8)]);
          w1a = mfma32(pa, vb, w1a);
        }
        {
          const int d = 32 + lo5;
          bf16x8 vb = ld8s(&Vl[d*64 + ((chunk ^ (d&7))*8)]);
          w1b = mfma32(pa, vb, w1b);
        }
      }
    }
  }

  // finalize bins -> CS
  bin0  += __shfl_xor(bin0, 32, 64);
  bin20 += __shfl_xor(bin20, 32, 64);
  if (hi == 0){
    CS[qrow*32 + (0  ^ ((qrow&3)<<3))] = f2b(bin0);
    CS[qrow*32 + (20 ^ ((qrow&3)<<3))] = f2b(bin20);
  }
  __syncthreads();

  // W2 = CS x rel_vT  (D[m=q][n=d], same layout as w1)
  f32x16 w2a = z16(), w2b = z16();
#pragma unroll
  for (int c2=0;c2<2;++c2){
    const int arow = wid*32 + lo5;
    bf16x8 cf  = ld8s(&CS[arow*32 + ((16*c2 + 8*hi) ^ ((arow&3)<<3))]);
    const int d0 = lo5, d1 = 32 + lo5;
    bf16x8 rv0 = ld8s(&RVT[d0*32 + ((16*c2 + 8*hi) ^ ((d0&3)<<3))]);
    bf16x8 rv1 = ld8s(&RVT[d1*32 + ((16*c2 + 8*hi) ^ ((d1&3)<<3))]);
    w2a = mfma32(cf, rv0, w2a);
    w2b = mfma32(cf, rv1, w2b);
  }

  float* sl = slab + (size_t)ks*16*2048*64 + (size_t)bh*2048*64;
#pragma unroll
  for (int r=0;r<16;++r){
    const int q = q0 + wid*32 + (r&3) + 8*(r>>2) + 4*hi;
    sl[(size_t)q*64 + lo5]      = w1a[r] + w2a[r];
    sl[(size_t)q*64 + 32 + lo5] = w1b[r] + w2b[r];
  }
}

// ---------------------------------------------------------------------------
// combine: x[b][s][h*64+dh] = bf16(slab0 + slab1)
// ---------------------------------------------------------------------------
__global__ __launch_bounds__(256) void combine_kernel(const float* s0, const float* s1, short* xb){
  const size_t i4 = ((size_t)blockIdx.x*256 + threadIdx.x)*4;
  float4 a = *(const float4*)(s0 + i4);
  float4 c = *(const float4*)(s1 + i4);
  const int bh = (int)(i4 >> 17);
  const int rem = (int)(i4 & 131071);
  const int s = rem >> 6, dh = rem & 63;
  const size_t xi = ((size_t)(bh>>3)*2048 + s)*512 + (bh&7)*64 + dh;
  short4v o = { f2b(a.x+c.x), f2b(a.y+c.y), f2b(a.z+c.z), f2b(a.w+c.w) };
  *(short4v*)(xb + xi) = o;
}

// ---------------------------------------------------------------------------
extern "C" void kernel_launch(void* const* d_in, const int* in_sizes, int n_in,
                              void* d_out, int out_size, void* d_ws, size_t ws_size,
                              hipStream_t stream) {
  (void)in_sizes; (void)n_in; (void)out_size; (void)ws_size;
  const float* q    = (const float*)d_in[0];
  const float* k    = (const float*)d_in[1];
  const float* v    = (const float*)d_in[2];
  // d_in[3] = mask (unused by reference math)
  const float* Wq   = (const float*)d_in[4];
  const float* bq   = (const float*)d_in[5];
  const float* Wk   = (const float*)d_in[6];
  const float* bk   = (const float*)d_in[7];
  const float* Wv   = (const float*)d_in[8];
  const float* bv   = (const float*)d_in[9];
  const float* W0   = (const float*)d_in[10];
  const float* b0   = (const float*)d_in[11];
  const float* relk = (const float*)d_in[12];
  const float* relv = (const float*)d_in[13];
  float* out = (float*)d_out;
  char* ws = (char*)d_ws;

  short* WTq = (short*)(ws);
  short* WTk = WTq + 512*512;
  short* WTv = WTk + 512*512;
  short* WT0 = WTv + 512*512;
  short* Qp  = (short*)(ws + ((size_t)2<<20));
  short* Kp  = (short*)(ws + ((size_t)6<<20));
  short* Vp  = (short*)(ws + ((size_t)10<<20));
  short* Vt  = (short*)(ws + ((size_t)14<<20));
  float* slab= (float*)(ws + ((size_t)18<<20));   // 2 x [16][2048][64] fp32 = 16 MB
  short* xb  = (short*)(ws + ((size_t)34<<20));   // 4 MB

  WtArgs wa = { {Wq, Wk, Wv, W0}, {WTq, WTk, WTv, WT0} };
  wt_kernel<<<dim3(8,8,4), 256, 0, stream>>>(wa);

  ProjArgs pa = { {q, k, v}, {WTq, WTk, WTv}, {bq, bk, bv}, {Qp, Kp, Vp} };
  proj_gemm<<<dim3(32,8,3), 256, 0, stream>>>(pa);

  vt_kernel<<<dim3(32,16), 256, 0, stream>>>(Vp, Vt);

  attn_kernel<<<dim3(16,16,2), 256, 0, stream>>>(Qp, Kp, Vt, relk, relv, slab);

  combine_kernel<<<2048, 256, 0, stream>>>(slab, slab + (size_t)16*2048*64, xb);

  out_gemm<<<dim3(32,8), 256, 0, stream>>>(xb, WT0, b0, out);
}

// Round 3
// 91.048 us; speedup vs baseline: 1.0194x; 1.0194x over previous
//
#include <hip/hip_runtime.h>
#include <hip/hip_bf16.h>

// Problem constants
// B=2, S=2048, D=512, H=8, DH=64, P=10, M = B*S = 4096
// scores = (QK^T + Q.rel_k[clamp])/sqrt(512); out = (scores.V + scores.rel_v) @ W0 + b0

typedef __attribute__((ext_vector_type(8)))  short  short8;
typedef __attribute__((ext_vector_type(4)))  short  short4v;
typedef __attribute__((ext_vector_type(4)))  int    int4v;
typedef __attribute__((ext_vector_type(16))) float  f32x16;
typedef __attribute__((ext_vector_type(8)))  __bf16 bf16x8;

#define DEV static __device__ __forceinline__

constexpr float INV_SCALE = 0.044194173824159216f; // 1/sqrt(512)

DEV unsigned short f2bs(float f){ __hip_bfloat16 h = __float2bfloat16(f); unsigned short u; __builtin_memcpy(&u,&h,2); return u; }
DEV short f2b(float f){ return (short)f2bs(f); }
DEV float b2f(short s){ unsigned u = ((unsigned)(unsigned short)s)<<16; float f; __builtin_memcpy(&f,&u,4); return f; }
DEV int   pk2(float a, float b){ return (int)((unsigned)f2bs(a) | ((unsigned)f2bs(b) << 16)); }
DEV bf16x8 ld8s(const short* p){ return __builtin_bit_cast(bf16x8, *(const short8*)p); }
DEV f32x16 z16(){ f32x16 z;
#pragma unroll
  for (int i=0;i<16;++i) z[i]=0.f;
  return z; }
DEV f32x16 mfma32(bf16x8 a, bf16x8 b, f32x16 c){ return __builtin_amdgcn_mfma_f32_32x32x16_bf16(a,b,c,0,0,0); }

// ---------------------------------------------------------------------------
// Weight transpose + cvt: WT[n][k] = bf16(W[k][n]) for Wq,Wk,Wv,W0
// ---------------------------------------------------------------------------
struct WtArgs { const float* W[4]; short* O[4]; };

__global__ __launch_bounds__(256) void wt_kernel(WtArgs args){
  const float* W = args.W[blockIdx.z];
  short* O = args.O[blockIdx.z];
  const int kt = blockIdx.x*64, nt = blockIdx.y*64;
  __shared__ float t[64][65];
  const int tid = threadIdx.x;
#pragma unroll
  for (int p=0;p<4;++p){
    int idx = p*1024 + tid*4; int r = idx>>6, c = idx&63;
    float4 v = *(const float4*)(W + (size_t)(kt+r)*512 + nt + c);
    t[r][c]=v.x; t[r][c+1]=v.y; t[r][c+2]=v.z; t[r][c+3]=v.w;
  }
  __syncthreads();
#pragma unroll
  for (int p=0;p<4;++p){
    int idx = p*1024 + tid*4; int n = idx>>6, k = idx&63;
    short4v o = { f2b(t[k][n]), f2b(t[k+1][n]), f2b(t[k+2][n]), f2b(t[k+3][n]) };
    *(short4v*)(O + (size_t)(nt+n)*512 + kt + k) = o;
  }
}

// ---------------------------------------------------------------------------
// GEMM: C[M=4096][512] = A[4096][512] @ W[512][512] + bias  (B given as WT[n][k])
// BM=128, BN=64, BK=64; 4 waves, wave w owns rows [w*32,w*32+32), all 64 cols.
// LDS rows are 128B with 16B-chunk XOR swizzle (chunk ^ (row&7)).
// ---------------------------------------------------------------------------
template<bool AF32, bool OUTB16>
DEV void gemm_body(const void* A, const short* BT, const float* bias, void* C,
                   int m0, int n0, short* Alds, short* Blds){
  const int tid = threadIdx.x, lane = tid&63, wid = tid>>6, lo5 = lane&31, hi = lane>>5;
  f32x16 acc0 = z16(), acc1 = z16();
  for (int kt=0; kt<8; ++kt){
    const int k0 = kt*64;
    __syncthreads();
    {
      const int rr = tid>>3, c = tid&7;
#pragma unroll
      for (int p=0;p<4;++p){
        int row = p*32 + rr;
        short8 v;
        if (AF32){
          const float* ap = (const float*)A + (size_t)(m0+row)*512 + k0 + c*8;
          float4 x = *(const float4*)ap; float4 y = *(const float4*)(ap+4);
          v = short8{ f2b(x.x),f2b(x.y),f2b(x.z),f2b(x.w), f2b(y.x),f2b(y.y),f2b(y.z),f2b(y.w) };
        } else {
          v = *(const short8*)((const short*)A + (size_t)(m0+row)*512 + k0 + c*8);
        }
        *(short8*)&Alds[row*64 + ((c ^ (row&7))*8)] = v;
      }
#pragma unroll
      for (int p=0;p<2;++p){
        int row = p*32 + rr;
        short8 v = *(const short8*)(BT + (size_t)(n0+row)*512 + k0 + c*8);
        *(short8*)&Blds[row*64 + ((c ^ (row&7))*8)] = v;
      }
    }
    __syncthreads();
#pragma unroll
    for (int da=0; da<4; ++da){
      const int arow = wid*32 + lo5;
      bf16x8 af = ld8s(&Alds[arow*64 + (((2*da+hi) ^ (arow&7))*8)]);
      const int b0r = lo5, b1r = 32+lo5;
      bf16x8 bf0 = ld8s(&Blds[b0r*64 + (((2*da+hi) ^ (b0r&7))*8)]);
      bf16x8 bf1 = ld8s(&Blds[b1r*64 + (((2*da+hi) ^ (b1r&7))*8)]);
      acc0 = mfma32(af, bf0, acc0);
      acc1 = mfma32(af, bf1, acc1);
    }
  }
  const float bv0 = bias[n0 + lo5], bv1 = bias[n0 + 32 + lo5];
#pragma unroll
  for (int r=0;r<16;++r){
    const int m = m0 + wid*32 + (r&3) + 8*(r>>2) + 4*hi;
    const float v0 = acc0[r] + bv0, v1 = acc1[r] + bv1;
    if (OUTB16){
      ((short*)C)[(size_t)m*512 + n0 + lo5]      = f2b(v0);
      ((short*)C)[(size_t)m*512 + n0 + 32 + lo5] = f2b(v1);
    } else {
      ((float*)C)[(size_t)m*512 + n0 + lo5]      = v0;
      ((float*)C)[(size_t)m*512 + n0 + 32 + lo5] = v1;
    }
  }
}

struct ProjArgs { const float* A[3]; const short* BT[3]; const float* bias[3]; short* C[3]; };

__global__ __launch_bounds__(256) void proj_gemm(ProjArgs args){
  __shared__ short Alds[128*64];
  __shared__ short Blds[64*64];
  const int z = blockIdx.z;
  gemm_body<true,true>(args.A[z], args.BT[z], args.bias[z], args.C[z],
                       blockIdx.x*128, blockIdx.y*64, Alds, Blds);
}

__global__ __launch_bounds__(256) void out_gemm(const short* A, const short* BT, const float* bias, float* C){
  __shared__ short Alds[128*64];
  __shared__ short Blds[64*64];
  gemm_body<false,false>(A, BT, bias, C, blockIdx.x*128, blockIdx.y*64, Alds, Blds);
}

// ---------------------------------------------------------------------------
// V transpose per head: Vp[b][s][h*64+dh] -> Vt[(b*8+h)][dh][s]
// ---------------------------------------------------------------------------
__global__ __launch_bounds__(256) void vt_kernel(const short* Vp, short* Vt){
  const int bh = blockIdx.y, s0 = blockIdx.x*64;
  const int b = bh>>3, h = bh&7;
  __shared__ short t[64][72];
  const int tid = threadIdx.x;
#pragma unroll
  for (int p=0;p<2;++p){
    int row = p*32 + (tid>>3), cc = (tid&7)*8;
    short8 v = *(const short8*)(Vp + (size_t)(b*2048 + s0 + row)*512 + h*64 + cc);
#pragma unroll
    for (int i=0;i<8;++i) t[row][cc+i] = v[i];
  }
  __syncthreads();
#pragma unroll
  for (int p=0;p<2;++p){
    int d = p*32 + (tid>>3), sc = (tid&7)*8;
    short8 o;
#pragma unroll
    for (int i=0;i<8;++i) o[i] = t[sc+i][d];
    *(short8*)(Vt + ((size_t)bh*64 + d)*2048 + s0 + sc) = o;
  }
}

// ---------------------------------------------------------------------------
// Fused linear attention with relative position terms.
// Grid: (qt 0..15, bh 0..15, ks 0..3). 256 thr = 4 waves; wave owns 32 q rows.
// 4 blocks/CU (LDS 39424B x4 = 157.7KB). Per block: 8 k-tiles of 64 (512 k).
// T14 async staging: next tile's K/V global loads issued into registers right
// after the LDS-ready barrier; reg->LDS write happens at next iter top, so the
// full compute phase covers the global latency. Writes bf16 partials to slab.
// ---------------------------------------------------------------------------
__global__ __launch_bounds__(256,4) void attn_kernel(const short* Qp, const short* Kp, const short* Vt,
                                                     const float* relk_g, const float* relv_g, short* slab){
  const int qt = blockIdx.x, bh = blockIdx.y, ks = blockIdx.z;
  const int b = bh>>3, h = bh&7;
  const int tid = threadIdx.x, lane = tid&63, wid = tid>>6, lo5 = lane&31, hi = lane>>5;
  const int q0 = qt*128, qw = q0 + wid*32;

  __shared__ short Klds[64*64];
  __shared__ short Vl[64*64];
  __shared__ float Rq[128*21];
  __shared__ short CS[128*32];
  __shared__ short RVT[64*32];

  // init CS = 0; RVT[d][j] = bf16(rel_v[j][d]) (j<21 else 0), 16B-swizzled rows
  for (int i=tid; i<2048; i+=256) ((int*)CS)[i] = 0;
  for (int i=tid; i<2048; i+=256){
    int d = i>>5, j = i&31;
    RVT[d*32 + (j ^ ((d&3)<<3))] = (j<21) ? f2b(relv_g[j*64+d]) : (short)0;
  }

  // Q fragments (lane lo5 -> q row qw+lo5; elems 16*da + 8*hi + i)
  bf16x8 qf[4];
  {
    const short* Qrow = Qp + (size_t)(b*2048 + qw + lo5)*512 + h*64 + hi*8;
#pragma unroll
    for (int da=0;da<4;++da) qf[da] = ld8s(Qrow + da*16);
  }

  const short* Kg = Kp + (size_t)b*2048*512 + h*64;
  const short* Vg = Vt + (size_t)bh*64*2048;
  const int rr = tid>>3, cc8 = tid&7;

  // prefetch tile 0 into registers
  short8 kreg0, kreg1, vreg0, vreg1;
  {
    const int k0 = ks*512;
    kreg0 = *(const short8*)(Kg + (size_t)(k0+rr)*512 + cc8*8);
    kreg1 = *(const short8*)(Kg + (size_t)(k0+32+rr)*512 + cc8*8);
    vreg0 = *(const short8*)(Vg + (size_t)rr*2048 + k0 + cc8*8);
    vreg1 = *(const short8*)(Vg + (size_t)(32+rr)*2048 + k0 + cc8*8);
  }

  // Rq[q][j] = Q[q] . rel_k[j]  via 4 MFMAs (Q frags as A, rel_k rows as B cols)
  {
    f32x16 rq = z16();
    const int jr = lo5 <= 20 ? lo5 : 20;
    const float* rp = relk_g + jr*64 + hi*8;
#pragma unroll
    for (int da=0;da<4;++da){
      const float* p = rp + da*16;
      float4 x = *(const float4*)p; float4 y = *(const float4*)(p+4);
      short8 rb = { f2b(x.x),f2b(x.y),f2b(x.z),f2b(x.w), f2b(y.x),f2b(y.y),f2b(y.z),f2b(y.w) };
      rq = mfma32(qf[da], __builtin_bit_cast(bf16x8, rb), rq);
    }
    if (lo5 <= 20){
#pragma unroll
      for (int r=0;r<16;++r){
        int qoff = (r&3) + 8*(r>>2) + 4*hi;
        Rq[(wid*32 + qoff)*21 + lo5] = rq[r];
      }
    }
  }

  const int qrow = wid*32 + lo5;   // local q (s-domain: this lane's column)
  const int qg = q0 + qrow;        // global q
  __syncthreads();
  const float r0  = Rq[qrow*21 + 0];
  const float r20 = Rq[qrow*21 + 20];
  float bin0 = 0.f, bin20 = 0.f;
  f32x16 w1a = z16(), w1b = z16();

  for (int kt=0; kt<8; ++kt){
    const int k0 = ks*512 + kt*64;
    __syncthreads();   // previous tile's readers done -> LDS free
    {
      const int rowa = rr, rowb = 32 + rr;
      *(short8*)&Klds[rowa*64 + ((cc8 ^ (rowa&7))*8)] = kreg0;
      *(short8*)&Klds[rowb*64 + ((cc8 ^ (rowb&7))*8)] = kreg1;
      *(short8*)&Vl[rowa*64 + ((cc8 ^ (rowa&7))*8)] = vreg0;
      *(short8*)&Vl[rowb*64 + ((cc8 ^ (rowb&7))*8)] = vreg1;
    }
    __syncthreads();   // LDS ready
    if (kt < 7){       // issue next tile's loads; latency hides under compute
      const int kn = k0 + 64;
      kreg0 = *(const short8*)(Kg + (size_t)(kn+rr)*512 + cc8*8);
      kreg1 = *(const short8*)(Kg + (size_t)(kn+32+rr)*512 + cc8*8);
      vreg0 = *(const short8*)(Vg + (size_t)rr*2048 + kn + cc8*8);
      vreg1 = *(const short8*)(Vg + (size_t)(32+rr)*2048 + kn + cc8*8);
    }

#pragma unroll
    for (int ksub=0; ksub<2; ++ksub){
      const int kb = k0 + ksub*32;
      // scores^T: D[m=k][n=q]
      f32x16 acc = z16();
#pragma unroll
      for (int da=0;da<4;++da){
        const int arow = ksub*32 + lo5;
        bf16x8 af = ld8s(&Klds[arow*64 + (((2*da+hi) ^ (arow&7))*8)]);
        acc = mfma32(af, qf[da], acc);
      }
      float s[16];
      if (kb + 31 <= qw - 10){            // whole subtile strictly below diag-band for all wave rows
#pragma unroll
        for (int r=0;r<16;++r){ float sv = (acc[r] + r0)*INV_SCALE; bin0 += sv; s[r]=sv; }
      } else if (kb >= qw + 41){          // strictly above
#pragma unroll
        for (int r=0;r<16;++r){ float sv = (acc[r] + r20)*INV_SCALE; bin20 += sv; s[r]=sv; }
      } else {
#pragma unroll
        for (int r=0;r<16;++r){
          const int krow = kb + (r&3) + 8*(r>>2) + 4*hi;
          const int delta = krow - qg;
          float rel;
          if (delta <= -10) rel = r0;
          else if (delta >= 10) rel = r20;
          else rel = Rq[qrow*21 + delta + 10];
          const float sv = (acc[r] + rel)*INV_SCALE;
          if (delta <= -10) bin0 += sv;
          else if (delta >= 10) bin20 += sv;
          else CS[qrow*32 + ((delta+10) ^ ((qrow&3)<<3))] = f2b(sv);
          s[r] = sv;
        }
      }
      // repack scores into PV A-frags (k split across lane halves)
      const int x0 = pk2(s[0],s[1]),   x1 = pk2(s[2],s[3]);
      const int y0 = pk2(s[4],s[5]),   y1 = pk2(s[6],s[7]);
      const int x2 = pk2(s[8],s[9]),   x3 = pk2(s[10],s[11]);
      const int y2 = pk2(s[12],s[13]), y3 = pk2(s[14],s[15]);
      const int x0s=__shfl_xor(x0,32,64), x1s=__shfl_xor(x1,32,64);
      const int y0s=__shfl_xor(y0,32,64), y1s=__shfl_xor(y1,32,64);
      const int x2s=__shfl_xor(x2,32,64), x3s=__shfl_xor(x3,32,64);
      const int y2s=__shfl_xor(y2,32,64), y3s=__shfl_xor(y3,32,64);
      const bool lo = (hi==0);
      int4v A0 = { lo?x0:y0s, lo?x1:y1s, lo?x0s:y0, lo?x1s:y1 };
      int4v A1 = { lo?x2:y2s, lo?x3:y3s, lo?x2s:y2, lo?x3s:y3 };
      const bf16x8 pa0 = __builtin_bit_cast(bf16x8, A0);
      const bf16x8 pa1 = __builtin_bit_cast(bf16x8, A1);
#pragma unroll
      for (int c=0;c<2;++c){
        const bf16x8 pa = c ? pa1 : pa0;
        const int chunk = ksub*4 + 2*c + hi;
        {
          const int d = lo5;
          bf16x8 vb = ld8s(&Vl[d*64 + ((chunk ^ (d&7))*8)]);
          w1a = mfma32(pa, vb, w1a);
        }
        {
          const int d = 32 + lo5;
          bf16x8 vb = ld8s(&Vl[d*64 + ((chunk ^ (d&7))*8)]);
          w1b = mfma32(pa, vb, w1b);
        }
      }
    }
  }

  // finalize bins -> CS
  bin0  += __shfl_xor(bin0, 32, 64);
  bin20 += __shfl_xor(bin20, 32, 64);
  if (hi == 0){
    CS[qrow*32 + (0  ^ ((qrow&3)<<3))] = f2b(bin0);
    CS[qrow*32 + (20 ^ ((qrow&3)<<3))] = f2b(bin20);
  }
  __syncthreads();

  // W2 = CS x rel_vT  (D[m=q][n=d], same layout as w1)
  f32x16 w2a = z16(), w2b = z16();
#pragma unroll
  for (int c2=0;c2<2;++c2){
    const int arow = wid*32 + lo5;
    bf16x8 cf  = ld8s(&CS[arow*32 + ((16*c2 + 8*hi) ^ ((arow&3)<<3))]);
    const int d0 = lo5, d1 = 32 + lo5;
    bf16x8 rv0 = ld8s(&RVT[d0*32 + ((16*c2 + 8*hi) ^ ((d0&3)<<3))]);
    bf16x8 rv1 = ld8s(&RVT[d1*32 + ((16*c2 + 8*hi) ^ ((d1&3)<<3))]);
    w2a = mfma32(cf, rv0, w2a);
    w2b = mfma32(cf, rv1, w2b);
  }

  short* sl = slab + ((size_t)ks*16 + bh)*2048*64;
#pragma unroll
  for (int r=0;r<16;++r){
    const int q = q0 + wid*32 + (r&3) + 8*(r>>2) + 4*hi;
    sl[(size_t)q*64 + lo5]      = f2b(w1a[r] + w2a[r]);
    sl[(size_t)q*64 + 32 + lo5] = f2b(w1b[r] + w2b[r]);
  }
}

// ---------------------------------------------------------------------------
// combine: x[b][s][h*64+dh] = bf16(sum of 4 bf16 slabs)
// ---------------------------------------------------------------------------
__global__ __launch_bounds__(256) void combine_kernel(const short* slab, short* xb){
  const size_t i8 = ((size_t)blockIdx.x*256 + threadIdx.x)*8;
  const size_t SS = (size_t)16*2048*64;
  float acc[8];
#pragma unroll
  for (int j=0;j<8;++j) acc[j]=0.f;
#pragma unroll
  for (int s4=0;s4<4;++s4){
    short8 v = *(const short8*)(slab + s4*SS + i8);
#pragma unroll
    for (int j=0;j<8;++j) acc[j] += b2f(v[j]);
  }
  const int bh = (int)(i8 >> 17);
  const int rem = (int)(i8 & 131071);
  const int s = rem >> 6, dh = rem & 63;
  const size_t xi = ((size_t)(bh>>3)*2048 + s)*512 + (bh&7)*64 + dh;
  short8 o;
#pragma unroll
  for (int j=0;j<8;++j) o[j] = f2b(acc[j]);
  *(short8*)(xb + xi) = o;
}

// ---------------------------------------------------------------------------
extern "C" void kernel_launch(void* const* d_in, const int* in_sizes, int n_in,
                              void* d_out, int out_size, void* d_ws, size_t ws_size,
                              hipStream_t stream) {
  (void)in_sizes; (void)n_in; (void)out_size; (void)ws_size;
  const float* q    = (const float*)d_in[0];
  const float* k    = (const float*)d_in[1];
  const float* v    = (const float*)d_in[2];
  // d_in[3] = mask (unused by reference math)
  const float* Wq   = (const float*)d_in[4];
  const float* bq   = (const float*)d_in[5];
  const float* Wk   = (const float*)d_in[6];
  const float* bk   = (const float*)d_in[7];
  const float* Wv   = (const float*)d_in[8];
  const float* bv   = (const float*)d_in[9];
  const float* W0   = (const float*)d_in[10];
  const float* b0   = (const float*)d_in[11];
  const float* relk = (const float*)d_in[12];
  const float* relv = (const float*)d_in[13];
  float* out = (float*)d_out;
  char* ws = (char*)d_ws;

  short* WTq = (short*)(ws);
  short* WTk = WTq + 512*512;
  short* WTv = WTk + 512*512;
  short* WT0 = WTv + 512*512;
  short* Qp  = (short*)(ws + ((size_t)2<<20));
  short* Kp  = (short*)(ws + ((size_t)6<<20));
  short* Vp  = (short*)(ws + ((size_t)10<<20));
  short* Vt  = (short*)(ws + ((size_t)14<<20));
  short* slab= (short*)(ws + ((size_t)18<<20));   // 4 x [16][2048][64] bf16 = 16 MB
  short* xb  = (short*)(ws + ((size_t)34<<20));   // 4 MB

  WtArgs wa = { {Wq, Wk, Wv, W0}, {WTq, WTk, WTv, WT0} };
  wt_kernel<<<dim3(8,8,4), 256, 0, stream>>>(wa);

  ProjArgs pa = { {q, k, v}, {WTq, WTk, WTv}, {bq, bk, bv}, {Qp, Kp, Vp} };
  proj_gemm<<<dim3(32,8,3), 256, 0, stream>>>(pa);

  vt_kernel<<<dim3(32,16), 256, 0, stream>>>(Vp, Vt);

  attn_kernel<<<dim3(16,16,4), 256, 0, stream>>>(Qp, Kp, Vt, relk, relv, slab);

  combine_kernel<<<1024, 256, 0, stream>>>(slab, xb);

  out_gemm<<<dim3(32,8), 256, 0, stream>>>(xb, WT0, b0, out);
}